// Round 2
// baseline (182.826 us; speedup 1.0000x reference)
//
#include <hip/hip_runtime.h>
#include <math.h>

// Problem constants
#define KC 1024       // num codes
#define DD 256        // embedding dim
#define NROWS 32768   // 32 * 32 * 32 (B*H*W)
#define NELEM 8388608 // NROWS * DD

typedef _Float16 f16;
typedef __attribute__((ext_vector_type(8))) _Float16 f16x8;
typedef __attribute__((ext_vector_type(16))) float f32x16;

#define KEY_SCALE 2097152.0f   // 2^21; |score| <= ~0.63 -> |ikey| < 2^21
#define KEY_INV   (1.0f / 2097152.0f)

// ---------------------------------------------------------------------------
// prep: zero counts/loss64/done + c_sq (exact fp32) + emb -> fp16 swizzled
// grid 256 x 256.  emb_h layout: [kg 32][code 1024][8]
// ---------------------------------------------------------------------------
__global__ void vq_prep_kernel(const float* __restrict__ emb, f16* __restrict__ emb_h,
                               float* __restrict__ c_sq, int* __restrict__ counts,
                               float* __restrict__ loss64, unsigned* __restrict__ done) {
    const int tid = threadIdx.x;
    const int gt = blockIdx.x * 256 + tid;
    if (gt < KC) counts[gt] = 0;
    if (gt < 64) loss64[gt] = 0.0f;
    if (gt == 0) *done = 0u;
    {
        int k = blockIdx.x * 4 + (tid >> 6);
        int lane = tid & 63;
        float4 v = *(const float4*)(emb + (size_t)k * DD + lane * 4);
        float s = v.x * v.x + v.y * v.y + v.z * v.z + v.w * v.w;
        #pragma unroll
        for (int off = 32; off > 0; off >>= 1) s += __shfl_down(s, off);
        if (lane == 0) c_sq[k] = s;
    }
    if (gt < 32768) {
        int code = gt & 1023;
        int kg = gt >> 10;
        const float* p = emb + (size_t)code * DD + kg * 8;
        float4 v0 = *(const float4*)p;
        float4 v1 = *(const float4*)(p + 4);
        f16x8 hcv;
        hcv[0] = (f16)v0.x; hcv[1] = (f16)v0.y; hcv[2] = (f16)v0.z; hcv[3] = (f16)v0.w;
        hcv[4] = (f16)v1.x; hcv[5] = (f16)v1.y; hcv[6] = (f16)v1.z; hcv[7] = (f16)v1.w;
        *(f16x8*)(emb_h + (size_t)gt * 8) = hcv;
    }
}

// ---------------------------------------------------------------------------
// Fused main, 32 rows/block, 512 threads (8 waves), grid 1024.
// XCD-aware CHUNKED swizzle (bijective, 1024%8==0): lbid=(bid%8)*128+bid/8.
//   Each XCD owns 128 consecutive 32-row tiles = 4096 contiguous hw-rows, so
//   both 128B halves of every 256B out/z line live in ONE L2 -> full-line
//   evictions, no cross-XCD partial-line RMW (round-1 regression: WRITE_SIZE
//   doubled to 70.6MB because adjacent tiles round-robined onto different
//   XCDs; this restores ~33.6MB).
// Wave w owns codes [w*128,(w+1)*128) as 4 chunks of 32; ONE 32x32 acc
// per chunk + bk[16] packed argmin keys. counts/loss atomics deferred to
// after the out-writes; block losses spread over 64 slots.
// argmin key = trunc(score*2^21)*1024 + code  (monotone, first-min ties).
// loss per row: sum_c (q-z)^2 = score_min + ||z||^2.
// ---------------------------------------------------------------------------
__global__ __launch_bounds__(512, 6)
void vq_main_kernel(const float* __restrict__ z, const float* __restrict__ emb,
                    const f16* __restrict__ emb_h, const float* __restrict__ c_sq,
                    int* __restrict__ counts, float* __restrict__ loss64,
                    unsigned* __restrict__ done, float* __restrict__ out,
                    float* __restrict__ out_tail) {
    __shared__ __align__(16) char smem_raw[33280]; // z_s (A/B) then Qh (C)
    __shared__ int   bl_key[8][32];
    __shared__ float zsq_part[16][32];
    __shared__ int   idx_s[32];
    __shared__ float wsum[8];
    __shared__ int   last_flag;

    f16* z_s = (f16*)smem_raw;      // [kg 32][row 32][8]  = 16384 B
    float* Qh = (float*)smem_raw;   // [row 32][260]       = 33280 B

    const int tid = threadIdx.x;
    const int bid = blockIdx.x;
    const int lbid = (bid & 7) * 128 + (bid >> 3);   // chunked XCD swizzle
    const int n0 = lbid * 32;
    const int b = n0 >> 10;
    const int hw0 = n0 & 1023;

    // ---- Phase A: stage z tile fp16 + per-row ||z||^2 partials ----
    {
        const int r = tid & 31;
        const int kq = tid >> 5;   // 0..15, each covers 16 channels
        const float* zp = z + (size_t)b * (DD * 1024) + hw0 + r;
        float sq = 0.f;
        #pragma unroll
        for (int it = 0; it < 2; ++it) {
            int kg = kq * 2 + it;
            f16x8 hv;
            #pragma unroll
            for (int j = 0; j < 8; ++j) {
                float v = zp[(size_t)(kg * 8 + j) * 1024];
                sq += v * v;
                hv[j] = (f16)v;
            }
            *(f16x8*)&z_s[(kg * 32 + r) * 8] = hv;
        }
        zsq_part[kq][r] = sq;
    }
    __syncthreads();

    const int m = tid & 31;        // code-lane within 32-tile
    const int h = (tid >> 5) & 1;  // k-half
    const int w = tid >> 6;        // wave id 0..7

    int bk[16];
    #pragma unroll
    for (int s = 0; s < 16; ++s) bk[s] = 0x7FFFFFFF;

    // ---- Phase B: MFMA + running packed argmin ----
    for (int c = 0; c < 4; ++c) {
        const int code = w * 128 + c * 32 + m;
        const f16* ebp = emb_h + (size_t)h * 8192 + (size_t)code * 8;

        f32x16 acc;
        #pragma unroll
        for (int i = 0; i < 16; ++i) acc[i] = 0.f;

        #pragma unroll 4
        for (int ks = 0; ks < 16; ++ks) {
            f16x8 a0 = *(const f16x8*)(z_s + ((2 * ks + h) * 32 + m) * 8);
            f16x8 b0 = *(const f16x8*)(ebp + (size_t)ks * 16384);
            acc = __builtin_amdgcn_mfma_f32_32x32x16_f16(a0, b0, acc, 0, 0, 0);
        }

        const float cs = c_sq[code];
        #pragma unroll
        for (int reg = 0; reg < 16; ++reg) {
            float s0 = fmaf(-2.f, acc[reg], cs);
            int k0 = (int)(s0 * KEY_SCALE) * 1024 + code;
            bk[reg] = min(bk[reg], k0);
        }
    }

    // butterfly min across the 32 lanes of each k-half (rows stay distinct)
    #pragma unroll
    for (int s = 0; s < 16; ++s) {
        int k = bk[s];
        #pragma unroll
        for (int d = 16; d >= 1; d >>= 1) k = min(k, __shfl_xor(k, d));
        bk[s] = k;
    }
    if (m == 0) {
        #pragma unroll
        for (int s = 0; s < 16; ++s) {
            int row = (s & 3) + 8 * (s >> 2) + 4 * h;
            bl_key[w][row] = bk[s];
        }
    }
    __syncthreads();

    // combine 8 waves -> idx + per-block loss (atomics deferred to post-write)
    int my_idx = 0;
    float block_loss = 0.f;
    if (tid < 32) {
        int k = bl_key[0][tid];
        #pragma unroll
        for (int w2 = 1; w2 < 8; ++w2) k = min(k, bl_key[w2][tid]);
        my_idx = k & 1023;              // low 10 bits = code (two's complement safe)
        idx_s[tid] = my_idx;
        float zq = 0.f;
        #pragma unroll
        for (int p = 0; p < 16; ++p) zq += zsq_part[p][tid];
        float lr = (float)(k >> 10) * KEY_INV + zq;  // score_min + ||z||^2
        #pragma unroll
        for (int off = 16; off > 0; off >>= 1) lr += __shfl_down(lr, off);
        block_loss = lr;                // lane 0 valid
    }
    __syncthreads();

    // ---- Phase C1: Qh[r][c] = emb[idx[r]][c] fp32, stride 260 ----
    {
        int r = tid & 31;
        int part = tid >> 5;  // 0..15 -> 16 channels each
        const float* ep = emb + (size_t)idx_s[r] * DD + part * 16;
        float* qrow = Qh + r * 260 + part * 16;
        #pragma unroll
        for (int g = 0; g < 4; ++g)
            *(float4*)(qrow + g * 4) = *(const float4*)(ep + g * 4);
    }
    __syncthreads();

    // ---- Phase C2: coalesced channel-major writes ----
    {
        int r = tid & 31;
        int part = tid >> 5;
        const float* qr = Qh + r * 260;
        const size_t base = (size_t)b * (DD * 1024) + hw0 + r;
        #pragma unroll
        for (int g = 0; g < 4; ++g) {
            int c0 = part * 16 + g * 4;
            float4 v = *(const float4*)(qr + c0);
            out[base + (size_t)c0 * 1024] = v.x;
            out[base + (size_t)(c0 + 1) * 1024] = v.y;
            out[base + (size_t)(c0 + 2) * 1024] = v.z;
            out[base + (size_t)(c0 + 3) * 1024] = v.w;
        }
    }

    // ---- deferred stats: no barrier waits on these before the writes ----
    if (tid < 32) atomicAdd(&counts[my_idx], 1);
    if (tid == 0) atomicAdd(&loss64[lbid & 63], block_loss);

    // ---- last-block finalize ----
    __syncthreads();
    if (tid == 0) {
        __threadfence();
        last_flag = (atomicAdd(done, 1u) == 1023u) ? 1 : 0;
    }
    __syncthreads();
    if (last_flag) {
        __threadfence();
        float s = 0.f;
        for (int k = tid; k < KC; k += 512) {
            int cnt = atomicAdd(&counts[k], 0);
            float pr = (float)cnt * (1.0f / (float)NROWS);
            s += pr * logf(pr + 1e-10f);
        }
        #pragma unroll
        for (int off = 32; off > 0; off >>= 1) s += __shfl_down(s, off);
        if ((tid & 63) == 0) wsum[tid >> 6] = s;
        float loss_tot = 0.f;
        if (tid < 64) {
            float lv = atomicAdd(&loss64[tid], 0.0f);
            #pragma unroll
            for (int off = 32; off > 0; off >>= 1) lv += __shfl_down(lv, off);
            loss_tot = lv;              // lane 0 (tid 0) valid
        }
        __syncthreads();
        if (tid == 0) {
            float ent = 0.f;
            #pragma unroll
            for (int p = 0; p < 8; ++p) ent += wsum[p];
            out_tail[0] = 1.25f * loss_tot * (1.0f / (float)NELEM);
            out_tail[1] = expf(-ent);
        }
    }
}

// ---------------------------------------------------------------------------
extern "C" void kernel_launch(void* const* d_in, const int* in_sizes, int n_in,
                              void* d_out, int out_size, void* d_ws, size_t ws_size,
                              hipStream_t stream) {
    const float* z = (const float*)d_in[0];    // (32,256,32,32)
    const float* emb = (const float*)d_in[1];  // (1024,256)
    float* out = (float*)d_out;                // 8388608 + 2

    char* wsb = (char*)d_ws;
    f16* emb_h = (f16*)wsb;                    // 524288 B
    float* c_sq = (float*)(wsb + 524288);      // 4096 B
    int* counts = (int*)(wsb + 528384);        // 4096 B
    float* loss64 = (float*)(wsb + 532480);    // 256 B
    unsigned* done = (unsigned*)(wsb + 532736);

    hipLaunchKernelGGL(vq_prep_kernel, dim3(256), dim3(256), 0, stream,
                       emb, emb_h, c_sq, counts, loss64, done);
    hipLaunchKernelGGL(vq_main_kernel, dim3(1024), dim3(512), 0, stream,
                       z, emb, emb_h, c_sq, counts, loss64, done, out, out + NELEM);
}

// Round 3
// 169.123 us; speedup vs baseline: 1.0810x; 1.0810x over previous
//
#include <hip/hip_runtime.h>
#include <math.h>

// Problem constants
#define KC 1024       // num codes
#define DD 256        // embedding dim
#define NROWS 32768   // 32 * 32 * 32 (B*H*W)
#define NELEM 8388608 // NROWS * DD

typedef _Float16 f16;
typedef __attribute__((ext_vector_type(8))) _Float16 f16x8;
typedef __attribute__((ext_vector_type(16))) float f32x16;

#define KEY_SCALE 2097152.0f   // 2^21; |score| <= ~0.63 -> |ikey| < 2^21
#define KEY_INV   (1.0f / 2097152.0f)

// ---------------------------------------------------------------------------
// prep: zero counts/loss64/done/tile_done + key_ws=INT_MAX + c_sq (exact fp32)
// + emb -> fp16 swizzled.  grid 256 x 256.  emb_h layout: [kg 32][code 1024][8]
// ---------------------------------------------------------------------------
__global__ void vq_prep_kernel(const float* __restrict__ emb, f16* __restrict__ emb_h,
                               float* __restrict__ c_sq, int* __restrict__ counts,
                               float* __restrict__ loss64, unsigned* __restrict__ done,
                               unsigned* __restrict__ tile_done, int* __restrict__ key_ws) {
    const int tid = threadIdx.x;
    const int gt = blockIdx.x * 256 + tid;
    if (gt < KC) counts[gt] = 0;
    if (gt < 64) loss64[gt] = 0.0f;
    if (gt < 512) tile_done[gt] = 0u;
    if (gt == 0) *done = 0u;
    if (gt < 32768) key_ws[gt] = 0x7FFFFFFF;
    {
        int k = blockIdx.x * 4 + (tid >> 6);
        int lane = tid & 63;
        float4 v = *(const float4*)(emb + (size_t)k * DD + lane * 4);
        float s = v.x * v.x + v.y * v.y + v.z * v.z + v.w * v.w;
        #pragma unroll
        for (int off = 32; off > 0; off >>= 1) s += __shfl_down(s, off);
        if (lane == 0) c_sq[k] = s;
    }
    if (gt < 32768) {
        int code = gt & 1023;
        int kg = gt >> 10;
        const float* p = emb + (size_t)code * DD + kg * 8;
        float4 v0 = *(const float4*)p;
        float4 v1 = *(const float4*)(p + 4);
        f16x8 hcv;
        hcv[0] = (f16)v0.x; hcv[1] = (f16)v0.y; hcv[2] = (f16)v0.z; hcv[3] = (f16)v0.w;
        hcv[4] = (f16)v1.x; hcv[5] = (f16)v1.y; hcv[6] = (f16)v1.z; hcv[7] = (f16)v1.w;
        *(f16x8*)(emb_h + (size_t)gt * 8) = hcv;
    }
}

// ---------------------------------------------------------------------------
// Fused main, CODE-SPLIT PAIRS:
//   grid 1024, 512 threads (8 waves). tile = bid & 511 (64 rows, 256B
//   contiguity for z reads AND out writes); half = bid >> 9 selects codes
//   [half*512, half*512+512). Per-wave state: ONE 32x32 acc (16) + bk[16]
//   -> ~56 unified regs -> 8 waves/SIMD; LDS ~37KB -> 4 blocks/CU: the
//   ENTIRE grid is resident, phases fully desynchronized.
//   Cross-block argmin: device-scope atomicMin of packed int keys into
//   key_ws[32768]; second finisher of each pair (tile_done race) reads the
//   final keys and does loss/counts/gather/transpose/write. Phase-C staging
//   reuses dead z_s LDS in two 32-row passes (both halves of each 256B out
//   line written by the SAME block back-to-back -> L2 merges -> no RMW).
// argmin key = trunc(score*2^21)*1024 + code  (monotone, first-min ties;
// min is associative so cross-block atomicMin is exact).
// loss per row: sum_c (q-z)^2 = score_min + ||z||^2.
// ---------------------------------------------------------------------------
__global__ __launch_bounds__(512, 8)
void vq_main_kernel(const float* __restrict__ z, const float* __restrict__ emb,
                    const f16* __restrict__ emb_h, const float* __restrict__ c_sq,
                    int* __restrict__ counts, float* __restrict__ loss64,
                    unsigned* __restrict__ done, unsigned* __restrict__ tile_done,
                    int* __restrict__ key_ws, float* __restrict__ out,
                    float* __restrict__ out_tail) {
    __shared__ __align__(16) char smem_raw[33280]; // z_s (A/B) then Qh-half (C)
    __shared__ int   bl_key[4][64];
    __shared__ float zsq_part[8][64];
    __shared__ int   idx_s[64];
    __shared__ float wsum[8];
    __shared__ int   flag_s;

    f16* z_s = (f16*)smem_raw;      // [kg 32][row 64][8]  = 32768 B
    float* Qh = (float*)smem_raw;   // [row 32][260]       = 33280 B (C reuse)

    const int tid = threadIdx.x;
    const int tile = blockIdx.x & 511;
    const int half = blockIdx.x >> 9;
    const int n0 = tile * 64;
    const int b = n0 >> 10;
    const int hw0 = n0 & 1023;

    // ---- Phase A: stage z tile fp16 + per-row ||z||^2 partials ----
    {
        const int r = tid & 63;
        const int kq = tid >> 6;  // 0..7
        const float* zp = z + (size_t)b * (DD * 1024) + hw0 + r;
        float sq = 0.f;
        #pragma unroll
        for (int it = 0; it < 4; ++it) {
            int kg = kq * 4 + it;
            f16x8 hv;
            #pragma unroll
            for (int j = 0; j < 8; ++j) {
                float v = zp[(size_t)(kg * 8 + j) * 1024];
                sq += v * v;
                hv[j] = (f16)v;
            }
            *(f16x8*)&z_s[(kg * 64 + r) * 8] = hv;
        }
        zsq_part[kq][r] = sq;
    }
    __syncthreads();

    const int m = tid & 31;        // code-lane within 32-tile
    const int h = (tid >> 5) & 1;  // k-half
    const int w = tid >> 6;        // wave id 0..7
    const int rt = w & 1;          // row-tile (rows rt*32..rt*32+31)
    const int cg = w >> 1;         // code group 0..3 (128 codes each)

    int bk[16];
    #pragma unroll
    for (int s = 0; s < 16; ++s) bk[s] = 0x7FFFFFFF;

    // ---- Phase B: MFMA + running packed argmin over this block's 512 codes
    for (int c = 0; c < 4; ++c) {
        const int code = half * 512 + cg * 128 + c * 32 + m;
        const f16* ebp = emb_h + (size_t)h * 8192 + (size_t)code * 8;

        f32x16 acc;
        #pragma unroll
        for (int i = 0; i < 16; ++i) acc[i] = 0.f;

        #pragma unroll 4
        for (int ks = 0; ks < 16; ++ks) {
            f16x8 a0 = *(const f16x8*)(z_s + ((2 * ks + h) * 64 + rt * 32 + m) * 8);
            f16x8 b0 = *(const f16x8*)(ebp + (size_t)ks * 16384);
            acc = __builtin_amdgcn_mfma_f32_32x32x16_f16(a0, b0, acc, 0, 0, 0);
        }

        const float cs = c_sq[code];
        #pragma unroll
        for (int reg = 0; reg < 16; ++reg) {
            float s0 = fmaf(-2.f, acc[reg], cs);
            int k0 = (int)(s0 * KEY_SCALE) * 1024 + code;
            bk[reg] = min(bk[reg], k0);
        }
    }

    // butterfly min across 32 code-lanes (h halves carry distinct rows)
    #pragma unroll
    for (int s = 0; s < 16; ++s) {
        int k = bk[s];
        #pragma unroll
        for (int d = 16; d >= 1; d >>= 1) k = min(k, __shfl_xor(k, d));
        bk[s] = k;
    }
    if (m == 0) {
        #pragma unroll
        for (int s = 0; s < 16; ++s) {
            int row = rt * 32 + (s & 3) + 8 * (s >> 2) + 4 * h;
            bl_key[cg][row] = bk[s];
        }
    }
    __syncthreads();

    // combine 4 code-groups -> device-scope atomicMin into key_ws
    if (tid < 64) {
        int k = bl_key[0][tid];
        #pragma unroll
        for (int g = 1; g < 4; ++g) k = min(k, bl_key[g][tid]);
        atomicMin(&key_ws[tile * 64 + tid], k);
    }

    // ---- pair race: second finisher does the consumer phase ----
    __syncthreads();
    if (tid == 0) {
        __threadfence();
        unsigned old = atomicAdd(&tile_done[tile], 1u);
        flag_s = (old == 1u) ? 1 : 0;
        if (old == 1u) __threadfence();
    }
    __syncthreads();
    if (!flag_s) return;   // first finisher: keys published, done.

    // ---- consumer: final keys -> idx, loss; then gather+transpose+write ----
    int my_idx = 0;
    float block_loss = 0.f;
    if (tid < 64) {
        int k = atomicAdd(&key_ws[tile * 64 + tid], 0);  // coherent read
        my_idx = k & 1023;            // low 10 bits = code (two's complement safe)
        idx_s[tid] = my_idx;
        float zq = 0.f;
        #pragma unroll
        for (int p = 0; p < 8; ++p) zq += zsq_part[p][tid];
        float lr = (float)(k >> 10) * KEY_INV + zq;  // score_min + ||z||^2
        #pragma unroll
        for (int off = 32; off > 0; off >>= 1) lr += __shfl_down(lr, off);
        block_loss = lr;              // lane 0 valid
    }
    __syncthreads();

    // Phase C in two 32-row passes reusing z_s LDS as Qh[32][260]
    #pragma unroll
    for (int hh = 0; hh < 2; ++hh) {
        // C1: Qh[r][c] = emb[idx[hh*32+r]][c] fp32 (coalesced row gather)
        {
            int r = tid & 31;
            int part = tid >> 5;  // 0..15 -> 16 channels each
            const float* ep = emb + (size_t)idx_s[hh * 32 + r] * DD + part * 16;
            float* qrow = Qh + r * 260 + part * 16;
            #pragma unroll
            for (int g = 0; g < 4; ++g)
                *(float4*)(qrow + g * 4) = *(const float4*)(ep + g * 4);
        }
        __syncthreads();
        // C2: channel-major writes; same block writes both 128B halves of
        // every 256B line (hh=0 then hh=1) -> merges in L2.
        {
            int r = tid & 31;
            int part = tid >> 5;
            const float* qr = Qh + r * 260;
            const size_t base = (size_t)b * (DD * 1024) + hw0 + hh * 32 + r;
            #pragma unroll
            for (int g = 0; g < 4; ++g) {
                int c0 = part * 16 + g * 4;
                float4 v = *(const float4*)(qr + c0);
                out[base + (size_t)c0 * 1024] = v.x;
                out[base + (size_t)(c0 + 1) * 1024] = v.y;
                out[base + (size_t)(c0 + 2) * 1024] = v.z;
                out[base + (size_t)(c0 + 3) * 1024] = v.w;
            }
        }
        __syncthreads();
    }

    // ---- deferred stats ----
    if (tid < 64) atomicAdd(&counts[my_idx], 1);
    if (tid == 0) atomicAdd(&loss64[tile & 63], block_loss);

    // ---- last-consumer finalize (512 consumers total) ----
    __syncthreads();
    if (tid == 0) {
        __threadfence();
        flag_s = (atomicAdd(done, 1u) == 511u) ? 1 : 0;
    }
    __syncthreads();
    if (flag_s) {
        __threadfence();
        float s = 0.f;
        for (int k = tid; k < KC; k += 512) {
            int cnt = atomicAdd(&counts[k], 0);
            float pr = (float)cnt * (1.0f / (float)NROWS);
            s += pr * logf(pr + 1e-10f);
        }
        #pragma unroll
        for (int off = 32; off > 0; off >>= 1) s += __shfl_down(s, off);
        if ((tid & 63) == 0) wsum[tid >> 6] = s;
        __syncthreads();
        float loss_tot = 0.f;
        if (tid < 64) {
            float lv = atomicAdd(&loss64[tid], 0.0f);
            #pragma unroll
            for (int off = 32; off > 0; off >>= 1) lv += __shfl_down(lv, off);
            loss_tot = lv;            // lane 0 (tid 0) valid
        }
        if (tid == 0) {
            float ent = 0.f;
            #pragma unroll
            for (int p = 0; p < 8; ++p) ent += wsum[p];
            out_tail[0] = 1.25f * loss_tot * (1.0f / (float)NELEM);
            out_tail[1] = expf(-ent);
        }
    }
}

// ---------------------------------------------------------------------------
extern "C" void kernel_launch(void* const* d_in, const int* in_sizes, int n_in,
                              void* d_out, int out_size, void* d_ws, size_t ws_size,
                              hipStream_t stream) {
    const float* z = (const float*)d_in[0];    // (32,256,32,32)
    const float* emb = (const float*)d_in[1];  // (1024,256)
    float* out = (float*)d_out;                // 8388608 + 2

    char* wsb = (char*)d_ws;
    f16* emb_h = (f16*)wsb;                        // 524288 B
    float* c_sq = (float*)(wsb + 524288);          // 4096 B
    int* counts = (int*)(wsb + 528384);            // 4096 B
    float* loss64 = (float*)(wsb + 532480);        // 256 B
    unsigned* done = (unsigned*)(wsb + 532736);    // 4 B
    unsigned* tile_done = (unsigned*)(wsb + 532992); // 2048 B
    int* key_ws = (int*)(wsb + 535040);            // 131072 B

    hipLaunchKernelGGL(vq_prep_kernel, dim3(256), dim3(256), 0, stream,
                       emb, emb_h, c_sq, counts, loss64, done, tile_done, key_ws);
    hipLaunchKernelGGL(vq_main_kernel, dim3(1024), dim3(512), 0, stream,
                       z, emb, emb_h, c_sq, counts, loss64, done, tile_done, key_ws,
                       out, out + NELEM);
}

// Round 5
// 139.138 us; speedup vs baseline: 1.3140x; 1.2155x over previous
//
#include <hip/hip_runtime.h>
#include <math.h>

// Problem constants
#define KC 1024       // num codes
#define DD 256        // embedding dim
#define NROWS 32768   // 32 * 32 * 32 (B*H*W)
#define NELEM 8388608 // NROWS * DD

typedef _Float16 f16;
typedef __attribute__((ext_vector_type(8))) _Float16 f16x8;
typedef __attribute__((ext_vector_type(16))) float f32x16;

#define KEY_SCALE 2097152.0f   // 2^21; |score| <= ~0.63 -> |ikey| < 2^21
#define KEY_INV   (1.0f / 2097152.0f)

// ---------------------------------------------------------------------------
// prep: zero counts/loss64/done + c_sq (exact fp32) + emb -> fp16 swizzled
// grid 256 x 256.  emb_h layout: [kg 32][code 1024][8]
// ---------------------------------------------------------------------------
__global__ void vq_prep_kernel(const float* __restrict__ emb, f16* __restrict__ emb_h,
                               float* __restrict__ c_sq, int* __restrict__ counts,
                               float* __restrict__ loss64, unsigned* __restrict__ done) {
    const int tid = threadIdx.x;
    const int gt = blockIdx.x * 256 + tid;
    if (gt < KC) counts[gt] = 0;
    if (gt < 64) loss64[gt] = 0.0f;
    if (gt == 0) *done = 0u;
    {
        int k = blockIdx.x * 4 + (tid >> 6);
        int lane = tid & 63;
        float4 v = *(const float4*)(emb + (size_t)k * DD + lane * 4);
        float s = v.x * v.x + v.y * v.y + v.z * v.z + v.w * v.w;
        #pragma unroll
        for (int off = 32; off > 0; off >>= 1) s += __shfl_down(s, off);
        if (lane == 0) c_sq[k] = s;
    }
    if (gt < 32768) {
        int code = gt & 1023;
        int kg = gt >> 10;
        const float* p = emb + (size_t)code * DD + kg * 8;
        float4 v0 = *(const float4*)p;
        float4 v1 = *(const float4*)(p + 4);
        f16x8 hcv;
        hcv[0] = (f16)v0.x; hcv[1] = (f16)v0.y; hcv[2] = (f16)v0.z; hcv[3] = (f16)v0.w;
        hcv[4] = (f16)v1.x; hcv[5] = (f16)v1.y; hcv[6] = (f16)v1.z; hcv[7] = (f16)v1.w;
        *(f16x8*)(emb_h + (size_t)gt * 8) = hcv;
    }
}

// ---------------------------------------------------------------------------
// K1: argmin producer. grid 512, 512 threads (8 waves), 64 rows/block,
// ALL 1024 codes per block -> no cross-block sync of any kind.
// Wave w owns codes [w*128,(w+1)*128) AND both 32-row tiles, processed as
// 2 passes x 2 code-chunks with a 2x2 register block of 32x32 accumulators:
//   each a-frag ds_read feeds 2 MFMAs (rt0/rt1 share b), each b-frag L2 load
//   feeds 2 MFMAs (cc0/cc1 share a) -> LDS b128 reads halved vs R0,
//   b-frag L2 draw stays at 256MB aggregate (not R3's doubled 512MB).
// Outputs: idx_g[32768] (plain stores), counts (atomicAdd), loss64 partials.
// argmin key = trunc(score*2^21)*1024 + code (monotone, first-min ties;
// identical op order to prior rounds -> bit-identical idx).
// loss per row: sum_c (q-z)^2 = score_min + ||z||^2.
// ---------------------------------------------------------------------------
__global__ __launch_bounds__(512, 4)
void vq_argmin_kernel(const float* __restrict__ z, const f16* __restrict__ emb_h,
                      const float* __restrict__ c_sq, int* __restrict__ counts,
                      float* __restrict__ loss64, int* __restrict__ idx_g) {
    __shared__ __align__(16) f16 z_s[32 * 64 * 8];   // [kg 32][row 64][8] = 32768 B
    __shared__ int   bl_key[8][64];                   // 2048 B
    __shared__ float zsq_part[8][64];                 // 2048 B

    const int tid = threadIdx.x;
    const int n0 = blockIdx.x * 64;
    const int b = n0 >> 10;
    const int hw0 = n0 & 1023;

    ((int*)bl_key)[tid] = 0x7FFFFFFF;   // 512 ints, one per thread

    // ---- Phase A: stage z tile fp16 + per-row ||z||^2 partials ----
    {
        const int r = tid & 63;
        const int kq = tid >> 6;  // 0..7
        const float* zp = z + (size_t)b * (DD * 1024) + hw0 + r;
        float sq = 0.f;
        #pragma unroll
        for (int it = 0; it < 4; ++it) {
            int kg = kq * 4 + it;
            f16x8 hv;
            #pragma unroll
            for (int j = 0; j < 8; ++j) {
                float v = zp[(size_t)(kg * 8 + j) * 1024];
                sq += v * v;
                hv[j] = (f16)v;
            }
            *(f16x8*)&z_s[(kg * 64 + r) * 8] = hv;
        }
        zsq_part[kq][r] = sq;
    }
    __syncthreads();

    const int m = tid & 31;        // code-lane within 32-tile
    const int h = (tid >> 5) & 1;  // k-half (lane property)
    const int w = tid >> 6;        // wave id 0..7

    // ---- Phase B: 2 passes x (2 row-tiles x 2 code-chunks) register block
    for (int p = 0; p < 2; ++p) {
        const int code0 = w * 128 + p * 64 + m;
        const int code1 = code0 + 32;
        const f16* eb0 = emb_h + (size_t)h * 8192 + (size_t)code0 * 8;
        const f16* eb1 = emb_h + (size_t)h * 8192 + (size_t)code1 * 8;

        f32x16 acc00, acc01, acc10, acc11;  // acc[rt][cc]
        #pragma unroll
        for (int i = 0; i < 16; ++i) {
            acc00[i] = 0.f; acc01[i] = 0.f; acc10[i] = 0.f; acc11[i] = 0.f;
        }

        #pragma unroll 4
        for (int ks = 0; ks < 16; ++ks) {
            const f16* za = z_s + ((size_t)(2 * ks + h) * 64 + m) * 8;
            f16x8 a0 = *(const f16x8*)(za);            // rows m
            f16x8 a1 = *(const f16x8*)(za + 256);      // rows m+32
            f16x8 b0 = *(const f16x8*)(eb0 + (size_t)ks * 16384);
            f16x8 b1 = *(const f16x8*)(eb1 + (size_t)ks * 16384);
            acc00 = __builtin_amdgcn_mfma_f32_32x32x16_f16(a0, b0, acc00, 0, 0, 0);
            acc10 = __builtin_amdgcn_mfma_f32_32x32x16_f16(a1, b0, acc10, 0, 0, 0);
            acc01 = __builtin_amdgcn_mfma_f32_32x32x16_f16(a0, b1, acc01, 0, 0, 0);
            acc11 = __builtin_amdgcn_mfma_f32_32x32x16_f16(a1, b1, acc11, 0, 0, 0);
        }

        const float cs0 = c_sq[code0];
        const float cs1 = c_sq[code1];
        int bk0[16], bk1[16];
        #pragma unroll
        for (int reg = 0; reg < 16; ++reg) {
            float sA = fmaf(-2.f, acc00[reg], cs0);
            float sB = fmaf(-2.f, acc01[reg], cs1);
            int kA = (int)(sA * KEY_SCALE) * 1024 + code0;
            int kB = (int)(sB * KEY_SCALE) * 1024 + code1;
            bk0[reg] = min(kA, kB);
            sA = fmaf(-2.f, acc10[reg], cs0);
            sB = fmaf(-2.f, acc11[reg], cs1);
            kA = (int)(sA * KEY_SCALE) * 1024 + code0;
            kB = (int)(sB * KEY_SCALE) * 1024 + code1;
            bk1[reg] = min(kA, kB);
        }

        // butterfly min across the 32 code-lanes (h halves carry distinct rows)
        #pragma unroll
        for (int s = 0; s < 16; ++s) {
            int k0 = bk0[s], k1 = bk1[s];
            #pragma unroll
            for (int d = 16; d >= 1; d >>= 1) {
                k0 = min(k0, __shfl_xor(k0, d));
                k1 = min(k1, __shfl_xor(k1, d));
            }
            bk0[s] = k0; bk1[s] = k1;
        }
        if (m == 0) {
            #pragma unroll
            for (int s = 0; s < 16; ++s) {
                int row = (s & 3) + 8 * (s >> 2) + 4 * h;
                bl_key[w][row]      = min(bl_key[w][row],      bk0[s]);
                bl_key[w][32 + row] = min(bl_key[w][32 + row], bk1[s]);
            }
        }
    }
    __syncthreads();

    // ---- combine 8 waves -> idx store + counts + loss partial, then exit
    if (tid < 64) {
        int k = bl_key[0][tid];
        #pragma unroll
        for (int w2 = 1; w2 < 8; ++w2) k = min(k, bl_key[w2][tid]);
        int i = k & 1023;               // low 10 bits = code (two's complement safe)
        idx_g[n0 + tid] = i;
        atomicAdd(&counts[i], 1);
        float zq = 0.f;
        #pragma unroll
        for (int p2 = 0; p2 < 8; ++p2) zq += zsq_part[p2][tid];
        float lr = (float)(k >> 10) * KEY_INV + zq;  // score_min + ||z||^2
        #pragma unroll
        for (int off = 32; off > 0; off >>= 1) lr += __shfl_down(lr, off);
        if (tid == 0) atomicAdd(&loss64[blockIdx.x & 63], lr);
    }
}

// ---------------------------------------------------------------------------
// K2: consumer. grid 512, 512 threads, 64 rows/block. Reads idx (plain loads;
// kernel-boundary coherence), gathers emb rows -> LDS (two 32-row passes,
// 33.3KB), writes out channel-major in full 256B lines. Last block finalizes
// loss + perplexity (counts/loss64 complete since K1 finished).
// ---------------------------------------------------------------------------
__global__ __launch_bounds__(512, 4)
void vq_out_kernel(const float* __restrict__ emb, const int* __restrict__ idx_g,
                   const int* __restrict__ counts, const float* __restrict__ loss64,
                   unsigned* __restrict__ done, float* __restrict__ out,
                   float* __restrict__ out_tail) {
    __shared__ __align__(16) float Qh[32 * 260];   // 33280 B
    __shared__ int   idx_s[64];
    __shared__ float wsum[8];
    __shared__ int   flag_s;

    const int tid = threadIdx.x;
    const int n0 = blockIdx.x * 64;
    const int b = n0 >> 10;
    const int hw0 = n0 & 1023;

    if (tid < 64) idx_s[tid] = idx_g[n0 + tid];
    __syncthreads();

    #pragma unroll
    for (int hh = 0; hh < 2; ++hh) {
        // C1: Qh[r][c] = emb[idx[hh*32+r]][c] fp32 (coalesced row gather)
        {
            int r = tid & 31;
            int part = tid >> 5;  // 0..15 -> 16 channels each
            const float* ep = emb + (size_t)idx_s[hh * 32 + r] * DD + part * 16;
            float* qrow = Qh + r * 260 + part * 16;
            #pragma unroll
            for (int g = 0; g < 4; ++g)
                *(float4*)(qrow + g * 4) = *(const float4*)(ep + g * 4);
        }
        __syncthreads();
        // C2: channel-major writes; same block writes both 128B halves of
        // every 256B line (hh=0 then hh=1) -> full-line evictions.
        {
            int r = tid & 31;
            int part = tid >> 5;
            const float* qr = Qh + r * 260;
            const size_t base = (size_t)b * (DD * 1024) + hw0 + hh * 32 + r;
            #pragma unroll
            for (int g = 0; g < 4; ++g) {
                int c0 = part * 16 + g * 4;
                float4 v = *(const float4*)(qr + c0);
                out[base + (size_t)c0 * 1024] = v.x;
                out[base + (size_t)(c0 + 1) * 1024] = v.y;
                out[base + (size_t)(c0 + 2) * 1024] = v.z;
                out[base + (size_t)(c0 + 3) * 1024] = v.w;
            }
        }
        __syncthreads();
    }

    // ---- last-block finalize ----
    if (tid == 0) {
        __threadfence();
        flag_s = (atomicAdd(done, 1u) == 511u) ? 1 : 0;
    }
    __syncthreads();
    if (flag_s) {
        float s = 0.f;
        for (int k = tid; k < KC; k += 512) {
            float pr = (float)counts[k] * (1.0f / (float)NROWS);
            s += pr * logf(pr + 1e-10f);
        }
        #pragma unroll
        for (int off = 32; off > 0; off >>= 1) s += __shfl_down(s, off);
        if ((tid & 63) == 0) wsum[tid >> 6] = s;
        __syncthreads();
        float loss_tot = 0.f;
        if (tid < 64) {
            float lv = loss64[tid];
            #pragma unroll
            for (int off = 32; off > 0; off >>= 1) lv += __shfl_down(lv, off);
            loss_tot = lv;              // lane 0 (tid 0) valid
        }
        if (tid == 0) {
            float ent = 0.f;
            #pragma unroll
            for (int p = 0; p < 8; ++p) ent += wsum[p];
            out_tail[0] = 1.25f * loss_tot * (1.0f / (float)NELEM);
            out_tail[1] = expf(-ent);
        }
    }
}

// ---------------------------------------------------------------------------
extern "C" void kernel_launch(void* const* d_in, const int* in_sizes, int n_in,
                              void* d_out, int out_size, void* d_ws, size_t ws_size,
                              hipStream_t stream) {
    const float* z = (const float*)d_in[0];    // (32,256,32,32)
    const float* emb = (const float*)d_in[1];  // (1024,256)
    float* out = (float*)d_out;                // 8388608 + 2

    char* wsb = (char*)d_ws;
    f16* emb_h = (f16*)wsb;                        // 524288 B
    float* c_sq = (float*)(wsb + 524288);          // 4096 B
    int* counts = (int*)(wsb + 528384);            // 4096 B
    float* loss64 = (float*)(wsb + 532480);        // 256 B
    unsigned* done = (unsigned*)(wsb + 532736);    // 4 B
    int* idx_g = (int*)(wsb + 535040);             // 131072 B

    hipLaunchKernelGGL(vq_prep_kernel, dim3(256), dim3(256), 0, stream,
                       emb, emb_h, c_sq, counts, loss64, done);
    hipLaunchKernelGGL(vq_argmin_kernel, dim3(512), dim3(512), 0, stream,
                       z, emb_h, c_sq, counts, loss64, idx_g);
    hipLaunchKernelGGL(vq_out_kernel, dim3(512), dim3(512), 0, stream,
                       emb, idx_g, counts, loss64, done, out, out + NELEM);
}